// Round 7
// baseline (129.493 us; speedup 1.0000x reference)
//
#include <hip/hip_runtime.h>

#define N 4096
#define K 8
#define NPB 16                 // prep blocks (N/256)
#define S2_ROWS 4              // rows of A per S2 block
#define S2_BLOCKS (N / S2_ROWS)        // 1024
#define S1_IT 32               // i-rows per S1 block
#define S1_JT 1024             // j-cols per S1 block (4 per thread)
#define S1_BLOCKS ((N / S1_IT) * (N / S1_JT))  // 128*4 = 512

__device__ __forceinline__ float fast_exp2(float x) { return __builtin_amdgcn_exp2f(x); }
__device__ __forceinline__ float fast_log2(float x) { return __builtin_amdgcn_logf(x); }
__device__ __forceinline__ float fast_sqrt(float x) { return __builtin_amdgcn_sqrtf(x); }

// ---------------------------------------------------------------------------
// Pass 1: ZsT[n][k] = softmax_k(Z[:,n]); per-block partial
// Upart[blk][a*8+b] = sum_{n in blk} ZsT[n][a]*exp(C[n][b]).
// S[b] = sum_a U[a][b] (softmax rows sum to 1) -> no separate S reduction.
// Block 0 zeroes `out` (harness poisons it each call).
// ---------------------------------------------------------------------------
__global__ __launch_bounds__(256) void prep_stats(
    const float* __restrict__ Z, const float* __restrict__ C,
    float* __restrict__ ZsT, float* __restrict__ Upart, float* __restrict__ out)
{
    const int t = threadIdx.x;
    const int n = blockIdx.x * 256 + t;
    const float L2E = 1.44269504f;

    __shared__ float zsL[256 * K];
    __shared__ float eL[256 * K];
    __shared__ float red[4][64];

    if (blockIdx.x == 0 && t == 0) out[0] = 0.f;

    float z[K];
#pragma unroll
    for (int k = 0; k < K; ++k) z[k] = Z[k * N + n];   // coalesced column reads
    float zmax = z[0];
#pragma unroll
    for (int k = 1; k < K; ++k) zmax = fmaxf(zmax, z[k]);
    float zs[K];
    float zsum = 0.f;
#pragma unroll
    for (int k = 0; k < K; ++k) { zs[k] = fast_exp2((z[k] - zmax) * L2E); zsum += zs[k]; }
    const float inv = 1.f / zsum;
#pragma unroll
    for (int k = 0; k < K; ++k) zs[k] *= inv;

    float4* zst_p = (float4*)(ZsT + (size_t)n * K);
    zst_p[0] = make_float4(zs[0], zs[1], zs[2], zs[3]);
    zst_p[1] = make_float4(zs[4], zs[5], zs[6], zs[7]);

    const float4* c_p = (const float4*)(C + (size_t)n * K);
    const float4 c0 = c_p[0], c1 = c_p[1];
    float e[K];
    e[0] = fast_exp2(c0.x * L2E); e[1] = fast_exp2(c0.y * L2E);
    e[2] = fast_exp2(c0.z * L2E); e[3] = fast_exp2(c0.w * L2E);
    e[4] = fast_exp2(c1.x * L2E); e[5] = fast_exp2(c1.y * L2E);
    e[6] = fast_exp2(c1.z * L2E); e[7] = fast_exp2(c1.w * L2E);

#pragma unroll
    for (int k = 0; k < K; ++k) { zsL[t * K + k] = zs[k]; eL[t * K + k] = e[k]; }
    __syncthreads();

    const int cell = t & 63, q = t >> 6;
    const int a = cell >> 3, b = cell & 7;
    float s = 0.f;
    const int n0 = q * 64;
#pragma unroll 4
    for (int nn = 0; nn < 64; ++nn)
        s = fmaf(zsL[(n0 + nn) * K + a], eL[(n0 + nn) * K + b], s);
    red[q][cell] = s;
    __syncthreads();
    if (t < 64)
        Upart[blockIdx.x * 64 + t] = red[0][t] + red[1][t] + red[2][t] + red[3][t];
}

// ---------------------------------------------------------------------------
// Pass 2: fold Upart -> U, S; m[k] = sum_k' (U[k][k']/S[k']) * ZsT[n][k'].
// Emits two per-node tables (stride 12 floats):
//   RowConst[n]: [0..7] = -2*(m+1e-6), [8] = |m+1e-6|^2, [9] = beta_n*log2e
//   ColConst[n]: [0..7] =  m,          [8] = |m|^2,      [9] = beta_n*log2e
// so dist^2(i,j) = Row[i].s2 + Col[j].s2 + dot(Row[i].t, Col[j].m)
//               = |M_i + 1e-6 - M_j|^2  (the reference's one-sided shift).
// Subtracts the exact diagonal contribution from `out`.
// ---------------------------------------------------------------------------
__global__ __launch_bounds__(256) void prep_M(
    const float* __restrict__ ZsT, const float* __restrict__ Upart,
    const float* __restrict__ A, const float* __restrict__ beta,
    const float* __restrict__ a_ptr, float* __restrict__ RowConst,
    float* __restrict__ ColConst, float* __restrict__ out)
{
    const int t = threadIdx.x;
    const int n = blockIdx.x * 256 + t;
    const float L2E = 1.44269504f;
    const float LN2 = 0.69314718f;

    __shared__ float UL[64];
    __shared__ float SinvL[8];
    if (t < 64) {
        float s = 0.f;
#pragma unroll
        for (int blk = 0; blk < NPB; ++blk) s += Upart[blk * 64 + t];
        UL[t] = s;
    }
    __syncthreads();
    if (t < 8) {
        float s = 0.f;
#pragma unroll
        for (int a = 0; a < 8; ++a) s += UL[a * 8 + t];   // S[b] = sum_a U[a][b]
        SinvL[t] = 1.f / s;
    }
    __syncthreads();

    const float4* zst_p = (const float4*)(ZsT + (size_t)n * K);
    const float4 z0 = zst_p[0], z1 = zst_p[1];
    float w[K];
    w[0] = z0.x * SinvL[0]; w[1] = z0.y * SinvL[1]; w[2] = z0.z * SinvL[2]; w[3] = z0.w * SinvL[3];
    w[4] = z1.x * SinvL[4]; w[5] = z1.y * SinvL[5]; w[6] = z1.z * SinvL[6]; w[7] = z1.w * SinvL[7];
    float m[K];
#pragma unroll
    for (int k = 0; k < K; ++k) {
        float acc = 0.f;
#pragma unroll
        for (int kk = 0; kk < K; ++kk) acc = fmaf(UL[k * K + kk], w[kk], acc);
        m[k] = acc;
    }

    float v[K];
    float s2r = 0.f, s2c = 0.f;
#pragma unroll
    for (int k = 0; k < K; ++k) {
        v[k] = m[k] + 1e-6f;
        s2r = fmaf(v[k], v[k], s2r);
        s2c = fmaf(m[k], m[k], s2c);
    }
    const float bL2E = beta[n] * L2E;
    float4* rr_p = (float4*)(RowConst + (size_t)n * 12);
    rr_p[0] = make_float4(-2.f * v[0], -2.f * v[1], -2.f * v[2], -2.f * v[3]);
    rr_p[1] = make_float4(-2.f * v[4], -2.f * v[5], -2.f * v[6], -2.f * v[7]);
    rr_p[2] = make_float4(s2r, bL2E, 0.f, 0.f);
    float4* cc_p = (float4*)(ColConst + (size_t)n * 12);
    cc_p[0] = make_float4(m[0], m[1], m[2], m[3]);
    cc_p[1] = make_float4(m[4], m[5], m[6], m[7]);
    cc_p[2] = make_float4(s2c, bL2E, 0.f, 0.f);

    // exact diagonal contribution (subtracted from out)
    const float av = A[(size_t)n * N + n];
    const float theta = fmaf(-a_ptr[0], 2.8284271247e-6f, 2.f * beta[n]);
    const float ex = fast_exp2(theta * L2E);
    const float sp = LN2 * fast_log2(1.f + ex);
    float d = fmaf(theta, av, -sp);

    for (int off = 32; off > 0; off >>= 1) d += __shfl_down(d, off, 64);
    __shared__ float wsum[4];
    const int lane = t & 63, wid = t >> 6;
    if (lane == 0) wsum[wid] = d;
    __syncthreads();
    if (t == 0) atomicAdd(out, -(wsum[0] + wsum[1] + wsum[2] + wsum[3]));
}

// ---------------------------------------------------------------------------
// Pass 3 (fused): LL = ln2 * ( sum_hits t2*A  -  sum_all_pairs log2(1+2^t2) )
//   t2 = theta*log2e = bi*L2E + bj*L2E - a*L2E*dist.
// Blocks [0, S2_BLOCKS): S2 = stream A (trivial consumer: != 0 test), theta
//   chain only at hits (~1%). No barriers in the loop -> waves free-run and
//   the read stream saturates like a copy kernel (R2..R6 all pinned at
//   1.55 TB/s because EVERY element fed a 17-op dependent chain).
// Blocks [S2_BLOCKS, +S1_BLOCKS): S1 = softplus over all pairs, ZERO A
//   traffic, pure VALU/trans -> co-schedules with S2's memory waves (m114).
// ---------------------------------------------------------------------------
__global__ __launch_bounds__(256, 4) void pair_fused(
    const float* __restrict__ A, const float* __restrict__ RowConst,
    const float* __restrict__ ColConst, const float* __restrict__ a_ptr,
    float* __restrict__ out)
{
    const int t = threadIdx.x;
    const int lane = t & 63, w = t >> 6;
    const int bid = blockIdx.x;
    const float LN2 = 0.69314718f;
    const float naL2E = -a_ptr[0] * 1.44269504f;

    __shared__ __align__(16) float sL[S1_IT * 12];
    __shared__ float wsum[4];

    float acc = 0.f;

    if (bid < S2_BLOCKS) {
        // ---------------- S2: stream A, theta*A at nonzeros ----------------
        const int i0 = bid * S2_ROWS;
        if (t < S2_ROWS) {
            const float4* rp = (const float4*)(RowConst + (size_t)(i0 + t) * 12);
            float4* dp = (float4*)&sL[t * 12];
            dp[0] = rp[0]; dp[1] = rp[1]; dp[2] = rp[2];
        }
        __syncthreads();

        const float4* A4 = (const float4*)A;
        float4 cur[4], nxt[4];
#pragma unroll
        for (int k = 0; k < 4; ++k)
            nxt[k] = A4[(size_t)i0 * (N / 4) + k * 256 + t];

        float acc_t = 0.f;
        for (int rr = 0; rr < S2_ROWS; ++rr) {
#pragma unroll
            for (int k = 0; k < 4; ++k) cur[k] = nxt[k];
            if (rr + 1 < S2_ROWS) {
#pragma unroll
                for (int k = 0; k < 4; ++k)
                    nxt[k] = A4[(size_t)(i0 + rr + 1) * (N / 4) + k * 256 + t];
            }
            const float4 ti0 = *(const float4*)&sL[rr * 12];
            const float4 ti1 = *(const float4*)&sL[rr * 12 + 4];
            const float ci = sL[rr * 12 + 8];
            const float bi = sL[rr * 12 + 9];
#pragma unroll
            for (int k = 0; k < 4; ++k) {
                const int jb = (k * 256 + t) * 4;
                const float ae[4] = { cur[k].x, cur[k].y, cur[k].z, cur[k].w };
#pragma unroll
                for (int e = 0; e < 4; ++e) {
                    if (ae[e] != 0.f) {   // ~1% of lanes; predicated hit path
                        const float* cp = ColConst + (size_t)(jb + e) * 12;
                        const float4 m0 = *(const float4*)cp;
                        const float4 m1 = *(const float4*)(cp + 4);
                        const float2 cb = *(const float2*)(cp + 8);  // {|Mj|^2, bj*L2E}
                        float ss = ci + cb.x;
                        ss = fmaf(ti0.x, m0.x, ss); ss = fmaf(ti0.y, m0.y, ss);
                        ss = fmaf(ti0.z, m0.z, ss); ss = fmaf(ti0.w, m0.w, ss);
                        ss = fmaf(ti1.x, m1.x, ss); ss = fmaf(ti1.y, m1.y, ss);
                        ss = fmaf(ti1.z, m1.z, ss); ss = fmaf(ti1.w, m1.w, ss);
                        ss = fmaxf(ss, 0.f);
                        const float dist = fast_sqrt(ss);
                        const float t2 = fmaf(naL2E, dist, bi + cb.y);
                        acc_t = fmaf(t2, ae[e], acc_t);   // A is 0/1 but keep general
                    }
                }
            }
        }
        acc = LN2 * acc_t;
    } else {
        // ---------------- S1: softplus over ALL pairs, no A ----------------
        const int s = bid - S2_BLOCKS;
        const int it = s & (N / S1_IT - 1);   // 0..127
        const int jt = s >> 7;                // 0..3
        const int i0 = it * S1_IT;
        const int j0 = jt * S1_JT + 4 * t;

        if (t < S1_IT) {
            const float4* rp = (const float4*)(RowConst + (size_t)(i0 + t) * 12);
            float4* dp = (float4*)&sL[t * 12];
            dp[0] = rp[0]; dp[1] = rp[1]; dp[2] = rp[2];
        }
        __syncthreads();

        float4 mj0[4], mj1[4];
        float nj[4], bj[4];
#pragma unroll
        for (int c = 0; c < 4; ++c) {
            const float* cp = ColConst + (size_t)(j0 + c) * 12;
            mj0[c] = *(const float4*)cp;
            mj1[c] = *(const float4*)(cp + 4);
            const float2 cb = *(const float2*)(cp + 8);
            nj[c] = cb.x; bj[c] = cb.y;
        }

        float acc_l = 0.f;
        for (int r = 0; r < S1_IT; ++r) {
            const float4 ti0 = *(const float4*)&sL[r * 12];   // uniform -> broadcast
            const float4 ti1 = *(const float4*)&sL[r * 12 + 4];
            const float ci = sL[r * 12 + 8];
            const float bi = sL[r * 12 + 9];
#pragma unroll
            for (int c = 0; c < 4; ++c) {
                float ss = ci + nj[c];
                ss = fmaf(ti0.x, mj0[c].x, ss); ss = fmaf(ti0.y, mj0[c].y, ss);
                ss = fmaf(ti0.z, mj0[c].z, ss); ss = fmaf(ti0.w, mj0[c].w, ss);
                ss = fmaf(ti1.x, mj1[c].x, ss); ss = fmaf(ti1.y, mj1[c].y, ss);
                ss = fmaf(ti1.z, mj1[c].z, ss); ss = fmaf(ti1.w, mj1[c].w, ss);
                ss = fmaxf(ss, 0.f);
                const float dist = fast_sqrt(ss);
                const float t2 = fmaf(naL2E, dist, bi + bj[c]);
                acc_l += fast_log2(1.f + fast_exp2(t2));   // softplus/ln2
            }
        }
        acc = -LN2 * acc_l;
    }

    // block reduction -> one atomic per block
    for (int off = 32; off > 0; off >>= 1) acc += __shfl_down(acc, off, 64);
    if (lane == 0) wsum[w] = acc;
    __syncthreads();
    if (t == 0) atomicAdd(out, wsum[0] + wsum[1] + wsum[2] + wsum[3]);
}

extern "C" void kernel_launch(void* const* d_in, const int* in_sizes, int n_in,
                              void* d_out, int out_size, void* d_ws, size_t ws_size,
                              hipStream_t stream)
{
    const float* A    = (const float*)d_in[0];   // [N,N]
    const float* beta = (const float*)d_in[1];   // [N]
    const float* a    = (const float*)d_in[2];   // [1]
    const float* Z    = (const float*)d_in[3];   // [K,N]
    const float* C    = (const float*)d_in[4];   // [N,K]
    float* out = (float*)d_out;

    float* ws       = (float*)d_ws;
    float* ZsT      = ws;                             // N*K floats
    float* Upart    = ws + (size_t)N * K;             // NPB*64 floats
    float* RowConst = ws + (size_t)N * K + NPB * 64;  // N*12 floats
    float* ColConst = RowConst + (size_t)N * 12;      // N*12 floats

    prep_stats<<<NPB, 256, 0, stream>>>(Z, C, ZsT, Upart, out);
    prep_M<<<NPB, 256, 0, stream>>>(ZsT, Upart, A, beta, a, RowConst, ColConst, out);

    pair_fused<<<S2_BLOCKS + S1_BLOCKS, 256, 0, stream>>>(A, RowConst, ColConst, a, out);
}

// Round 8
// 122.423 us; speedup vs baseline: 1.0577x; 1.0577x over previous
//
#include <hip/hip_runtime.h>

#define N 4096
#define K 8
#define NPB 16                 // prep blocks (N/256)
#define S2_ROWS 4              // rows of A per S2 block
#define S2_BLOCKS (N / S2_ROWS)        // 1024
#define S1_IT 32               // i-rows per S1 block
#define S1_JT 1024             // j-cols per S1 block (4 per thread)
#define S1_BLOCKS ((N / S1_IT) * (N / S1_JT))  // 128*4 = 512
#define HCAP 1024              // per-block hit list capacity (mean ~164)

__device__ __forceinline__ float fast_exp2(float x) { return __builtin_amdgcn_exp2f(x); }
__device__ __forceinline__ float fast_log2(float x) { return __builtin_amdgcn_logf(x); }
__device__ __forceinline__ float fast_sqrt(float x) { return __builtin_amdgcn_sqrtf(x); }

// ---------------------------------------------------------------------------
// Pass 1: ZsT[n][k] = softmax_k(Z[:,n]); per-block partial
// Upart[blk][a*8+b] = sum_{n in blk} ZsT[n][a]*exp(C[n][b]).
// S[b] = sum_a U[a][b] (softmax rows sum to 1) -> no separate S reduction.
// Block 0 zeroes `out` (harness poisons it each call).
// ---------------------------------------------------------------------------
__global__ __launch_bounds__(256) void prep_stats(
    const float* __restrict__ Z, const float* __restrict__ C,
    float* __restrict__ ZsT, float* __restrict__ Upart, float* __restrict__ out)
{
    const int t = threadIdx.x;
    const int n = blockIdx.x * 256 + t;
    const float L2E = 1.44269504f;

    __shared__ float zsL[256 * K];
    __shared__ float eL[256 * K];
    __shared__ float red[4][64];

    if (blockIdx.x == 0 && t == 0) out[0] = 0.f;

    float z[K];
#pragma unroll
    for (int k = 0; k < K; ++k) z[k] = Z[k * N + n];   // coalesced column reads
    float zmax = z[0];
#pragma unroll
    for (int k = 1; k < K; ++k) zmax = fmaxf(zmax, z[k]);
    float zs[K];
    float zsum = 0.f;
#pragma unroll
    for (int k = 0; k < K; ++k) { zs[k] = fast_exp2((z[k] - zmax) * L2E); zsum += zs[k]; }
    const float inv = 1.f / zsum;
#pragma unroll
    for (int k = 0; k < K; ++k) zs[k] *= inv;

    float4* zst_p = (float4*)(ZsT + (size_t)n * K);
    zst_p[0] = make_float4(zs[0], zs[1], zs[2], zs[3]);
    zst_p[1] = make_float4(zs[4], zs[5], zs[6], zs[7]);

    const float4* c_p = (const float4*)(C + (size_t)n * K);
    const float4 c0 = c_p[0], c1 = c_p[1];
    float e[K];
    e[0] = fast_exp2(c0.x * L2E); e[1] = fast_exp2(c0.y * L2E);
    e[2] = fast_exp2(c0.z * L2E); e[3] = fast_exp2(c0.w * L2E);
    e[4] = fast_exp2(c1.x * L2E); e[5] = fast_exp2(c1.y * L2E);
    e[6] = fast_exp2(c1.z * L2E); e[7] = fast_exp2(c1.w * L2E);

#pragma unroll
    for (int k = 0; k < K; ++k) { zsL[t * K + k] = zs[k]; eL[t * K + k] = e[k]; }
    __syncthreads();

    const int cell = t & 63, q = t >> 6;
    const int a = cell >> 3, b = cell & 7;
    float s = 0.f;
    const int n0 = q * 64;
#pragma unroll 4
    for (int nn = 0; nn < 64; ++nn)
        s = fmaf(zsL[(n0 + nn) * K + a], eL[(n0 + nn) * K + b], s);
    red[q][cell] = s;
    __syncthreads();
    if (t < 64)
        Upart[blockIdx.x * 64 + t] = red[0][t] + red[1][t] + red[2][t] + red[3][t];
}

// ---------------------------------------------------------------------------
// Pass 2: fold Upart -> U, S; m[k] = sum_k' (U[k][k']/S[k']) * ZsT[n][k'].
// Emits two per-node tables (stride 12 floats):
//   RowConst[n]: [0..7] = -2*(m+1e-6), [8] = |m+1e-6|^2, [9] = beta_n*log2e
//   ColConst[n]: [0..7] =  m,          [8] = |m|^2,      [9] = beta_n*log2e
// dist^2(i,j) = Row[i].s2 + Col[j].s2 + dot(Row[i].t, Col[j].m).
// Subtracts the exact diagonal contribution from `out`.
// ---------------------------------------------------------------------------
__global__ __launch_bounds__(256) void prep_M(
    const float* __restrict__ ZsT, const float* __restrict__ Upart,
    const float* __restrict__ A, const float* __restrict__ beta,
    const float* __restrict__ a_ptr, float* __restrict__ RowConst,
    float* __restrict__ ColConst, float* __restrict__ out)
{
    const int t = threadIdx.x;
    const int n = blockIdx.x * 256 + t;
    const float L2E = 1.44269504f;
    const float LN2 = 0.69314718f;

    __shared__ float UL[64];
    __shared__ float SinvL[8];
    if (t < 64) {
        float s = 0.f;
#pragma unroll
        for (int blk = 0; blk < NPB; ++blk) s += Upart[blk * 64 + t];
        UL[t] = s;
    }
    __syncthreads();
    if (t < 8) {
        float s = 0.f;
#pragma unroll
        for (int a = 0; a < 8; ++a) s += UL[a * 8 + t];   // S[b] = sum_a U[a][b]
        SinvL[t] = 1.f / s;
    }
    __syncthreads();

    const float4* zst_p = (const float4*)(ZsT + (size_t)n * K);
    const float4 z0 = zst_p[0], z1 = zst_p[1];
    float w[K];
    w[0] = z0.x * SinvL[0]; w[1] = z0.y * SinvL[1]; w[2] = z0.z * SinvL[2]; w[3] = z0.w * SinvL[3];
    w[4] = z1.x * SinvL[4]; w[5] = z1.y * SinvL[5]; w[6] = z1.z * SinvL[6]; w[7] = z1.w * SinvL[7];
    float m[K];
#pragma unroll
    for (int k = 0; k < K; ++k) {
        float acc = 0.f;
#pragma unroll
        for (int kk = 0; kk < K; ++kk) acc = fmaf(UL[k * K + kk], w[kk], acc);
        m[k] = acc;
    }

    float v[K];
    float s2r = 0.f, s2c = 0.f;
#pragma unroll
    for (int k = 0; k < K; ++k) {
        v[k] = m[k] + 1e-6f;
        s2r = fmaf(v[k], v[k], s2r);
        s2c = fmaf(m[k], m[k], s2c);
    }
    const float bL2E = beta[n] * L2E;
    float4* rr_p = (float4*)(RowConst + (size_t)n * 12);
    rr_p[0] = make_float4(-2.f * v[0], -2.f * v[1], -2.f * v[2], -2.f * v[3]);
    rr_p[1] = make_float4(-2.f * v[4], -2.f * v[5], -2.f * v[6], -2.f * v[7]);
    rr_p[2] = make_float4(s2r, bL2E, 0.f, 0.f);
    float4* cc_p = (float4*)(ColConst + (size_t)n * 12);
    cc_p[0] = make_float4(m[0], m[1], m[2], m[3]);
    cc_p[1] = make_float4(m[4], m[5], m[6], m[7]);
    cc_p[2] = make_float4(s2c, bL2E, 0.f, 0.f);

    // exact diagonal contribution (subtracted from out)
    const float av = A[(size_t)n * N + n];
    const float theta = fmaf(-a_ptr[0], 2.8284271247e-6f, 2.f * beta[n]);
    const float ex = fast_exp2(theta * L2E);
    const float sp = LN2 * fast_log2(1.f + ex);
    float d = fmaf(theta, av, -sp);

    for (int off = 32; off > 0; off >>= 1) d += __shfl_down(d, off, 64);
    __shared__ float wsum[4];
    const int lane = t & 63, wid = t >> 6;
    if (lane == 0) wsum[wid] = d;
    __syncthreads();
    if (t == 0) atomicAdd(out, -(wsum[0] + wsum[1] + wsum[2] + wsum[3]));
}

// ---------------------------------------------------------------------------
// Pass 3 (fused):
// S2 blocks: TWO-PHASE sparse. Phase A sniffs A in 8-deep float4 batches
//   (combined-sum test; A is 0/1 so sums can't cancel) and pushes hit
//   coordinates to an LDS list -- NO gathers, NO transcendentals in-stream.
//   Phase B (one barrier later) processes the ~164 hits densely: one hit per
//   lane, all ColConst gathers issue together -> ONE latency exposure per
//   block instead of ~120 serialized 300-cyc chains per wave (the R7 42 us).
// S1 blocks: softplus over all pairs, zero A traffic (unchanged from R7).
// ---------------------------------------------------------------------------
__global__ __launch_bounds__(256, 4) void pair_fused(
    const float* __restrict__ A, const float* __restrict__ RowConst,
    const float* __restrict__ ColConst, const float* __restrict__ a_ptr,
    float* __restrict__ out)
{
    const int t = threadIdx.x;
    const int lane = t & 63, w = t >> 6;
    const int bid = blockIdx.x;
    const float LN2 = 0.69314718f;
    const float naL2E = -a_ptr[0] * 1.44269504f;

    __shared__ __align__(16) float sL[S1_IT * 12];   // S1 row consts / S2 4-row consts
    __shared__ int hcnt;
    __shared__ int hbuf[HCAP];
    __shared__ float wsum[4];

    float acc = 0.f;

    if (bid < S2_BLOCKS) {
        // ================= S2: sniff stream + batched hit phase =============
        const int i0 = bid * S2_ROWS;
        if (t == 0) hcnt = 0;
        if (t < S2_ROWS) {
            const float4* rp = (const float4*)(RowConst + (size_t)(i0 + t) * 12);
            float4* dp = (float4*)&sL[t * 12];
            dp[0] = rp[0]; dp[1] = rp[1]; dp[2] = rp[2];
        }
        __syncthreads();

        const float4* A4 = (const float4*)A + (size_t)i0 * (N / 4);
        float acc_t = 0.f;

#pragma unroll
        for (int b = 0; b < 2; ++b) {       // 2 batches of 8 float4 (2 rows each)
            float4 v[8];
#pragma unroll
            for (int s = 0; s < 8; ++s) {
                const int r = b * 2 + (s >> 2);
                const int k = s & 3;
                v[s] = A4[r * (N / 4) + k * 256 + t];
            }
            float sm[8];
            float tot = 0.f;
#pragma unroll
            for (int s = 0; s < 8; ++s) {
                sm[s] = (v[s].x + v[s].y) + (v[s].z + v[s].w);
                tot += sm[s];
            }
            if (tot != 0.f) {               // ~28% of lanes per batch
#pragma unroll
                for (int s = 0; s < 8; ++s) {
                    if (sm[s] != 0.f) {
                        const int r = b * 2 + (s >> 2);
                        const int jb = ((s & 3) * 256 + t) * 4;
                        const float ae[4] = { v[s].x, v[s].y, v[s].z, v[s].w };
#pragma unroll
                        for (int e = 0; e < 4; ++e) {
                            if (ae[e] != 0.f) {
                                const int idx = atomicAdd(&hcnt, 1);
                                if (idx < HCAP) {
                                    hbuf[idx] = (r << 12) | (jb + e);
                                } else {
                                    // overflow fallback (statistically never)
                                    const float* cp = ColConst + (size_t)(jb + e) * 12;
                                    const float4 m0 = *(const float4*)cp;
                                    const float4 m1 = *(const float4*)(cp + 4);
                                    const float2 cb = *(const float2*)(cp + 8);
                                    const float4 ti0 = *(const float4*)&sL[r * 12];
                                    const float4 ti1 = *(const float4*)&sL[r * 12 + 4];
                                    float ss = sL[r * 12 + 8] + cb.x;
                                    ss = fmaf(ti0.x, m0.x, ss); ss = fmaf(ti0.y, m0.y, ss);
                                    ss = fmaf(ti0.z, m0.z, ss); ss = fmaf(ti0.w, m0.w, ss);
                                    ss = fmaf(ti1.x, m1.x, ss); ss = fmaf(ti1.y, m1.y, ss);
                                    ss = fmaf(ti1.z, m1.z, ss); ss = fmaf(ti1.w, m1.w, ss);
                                    ss = fmaxf(ss, 0.f);
                                    acc_t = fmaf(naL2E, fast_sqrt(ss), acc_t + sL[r * 12 + 9] + cb.y);
                                }
                            }
                        }
                    }
                }
            }
        }
        __syncthreads();

        // -------- phase B: dense hit processing (gathers batched) ----------
        const int cnt = min(hcnt, HCAP);
        for (int h = t; h < cnt; h += 256) {
            const int ecode = hbuf[h];
            const int r = ecode >> 12;
            const int j = ecode & 4095;
            const float* cp = ColConst + (size_t)j * 12;
            const float4 m0 = *(const float4*)cp;        // all gathers issue
            const float4 m1 = *(const float4*)(cp + 4);  // back-to-back: one
            const float2 cb = *(const float2*)(cp + 8);  // latency exposure
            const float4 ti0 = *(const float4*)&sL[r * 12];
            const float4 ti1 = *(const float4*)&sL[r * 12 + 4];
            float ss = sL[r * 12 + 8] + cb.x;
            ss = fmaf(ti0.x, m0.x, ss); ss = fmaf(ti0.y, m0.y, ss);
            ss = fmaf(ti0.z, m0.z, ss); ss = fmaf(ti0.w, m0.w, ss);
            ss = fmaf(ti1.x, m1.x, ss); ss = fmaf(ti1.y, m1.y, ss);
            ss = fmaf(ti1.z, m1.z, ss); ss = fmaf(ti1.w, m1.w, ss);
            ss = fmaxf(ss, 0.f);
            const float dist = fast_sqrt(ss);
            acc_t += fmaf(naL2E, dist, sL[r * 12 + 9] + cb.y);   // t2 (A==1)
        }
        acc = LN2 * acc_t;
    } else {
        // ================= S1: softplus over ALL pairs, no A ================
        const int s = bid - S2_BLOCKS;
        const int it = s & (N / S1_IT - 1);   // 0..127
        const int jt = s >> 7;                // 0..3
        const int i0 = it * S1_IT;
        const int j0 = jt * S1_JT + 4 * t;

        if (t < S1_IT) {
            const float4* rp = (const float4*)(RowConst + (size_t)(i0 + t) * 12);
            float4* dp = (float4*)&sL[t * 12];
            dp[0] = rp[0]; dp[1] = rp[1]; dp[2] = rp[2];
        }
        __syncthreads();

        float4 mj0[4], mj1[4];
        float nj[4], bj[4];
#pragma unroll
        for (int c = 0; c < 4; ++c) {
            const float* cp = ColConst + (size_t)(j0 + c) * 12;
            mj0[c] = *(const float4*)cp;
            mj1[c] = *(const float4*)(cp + 4);
            const float2 cb = *(const float2*)(cp + 8);
            nj[c] = cb.x; bj[c] = cb.y;
        }

        float acc_l = 0.f;
        for (int r = 0; r < S1_IT; ++r) {
            const float4 ti0 = *(const float4*)&sL[r * 12];   // uniform -> bcast
            const float4 ti1 = *(const float4*)&sL[r * 12 + 4];
            const float ci = sL[r * 12 + 8];
            const float bi = sL[r * 12 + 9];
#pragma unroll
            for (int c = 0; c < 4; ++c) {
                float ss = ci + nj[c];
                ss = fmaf(ti0.x, mj0[c].x, ss); ss = fmaf(ti0.y, mj0[c].y, ss);
                ss = fmaf(ti0.z, mj0[c].z, ss); ss = fmaf(ti0.w, mj0[c].w, ss);
                ss = fmaf(ti1.x, mj1[c].x, ss); ss = fmaf(ti1.y, mj1[c].y, ss);
                ss = fmaf(ti1.z, mj1[c].z, ss); ss = fmaf(ti1.w, mj1[c].w, ss);
                ss = fmaxf(ss, 0.f);
                const float dist = fast_sqrt(ss);
                const float t2 = fmaf(naL2E, dist, bi + bj[c]);
                acc_l += fast_log2(1.f + fast_exp2(t2));   // softplus/ln2
            }
        }
        acc = -LN2 * acc_l;
    }

    // block reduction -> one atomic per block
    for (int off = 32; off > 0; off >>= 1) acc += __shfl_down(acc, off, 64);
    if (lane == 0) wsum[w] = acc;
    __syncthreads();
    if (t == 0) atomicAdd(out, wsum[0] + wsum[1] + wsum[2] + wsum[3]);
}

extern "C" void kernel_launch(void* const* d_in, const int* in_sizes, int n_in,
                              void* d_out, int out_size, void* d_ws, size_t ws_size,
                              hipStream_t stream)
{
    const float* A    = (const float*)d_in[0];   // [N,N]
    const float* beta = (const float*)d_in[1];   // [N]
    const float* a    = (const float*)d_in[2];   // [1]
    const float* Z    = (const float*)d_in[3];   // [K,N]
    const float* C    = (const float*)d_in[4];   // [N,K]
    float* out = (float*)d_out;

    float* ws       = (float*)d_ws;
    float* ZsT      = ws;                             // N*K floats
    float* Upart    = ws + (size_t)N * K;             // NPB*64 floats
    float* RowConst = ws + (size_t)N * K + NPB * 64;  // N*12 floats
    float* ColConst = RowConst + (size_t)N * 12;      // N*12 floats

    prep_stats<<<NPB, 256, 0, stream>>>(Z, C, ZsT, Upart, out);
    prep_M<<<NPB, 256, 0, stream>>>(ZsT, Upart, A, beta, a, RowConst, ColConst, out);

    pair_fused<<<S2_BLOCKS + S1_BLOCKS, 256, 0, stream>>>(A, RowConst, ColConst, a, out);
}